// Round 4
// baseline (839.755 us; speedup 1.0000x reference)
//
#include <hip/hip_runtime.h>
#include <hip/hip_bf16.h>
#include <cstdint>

#define N_NODES 100000
#define N_EDGES 3200000

typedef __attribute__((ext_vector_type(8))) short short8;
typedef __attribute__((ext_vector_type(4))) float floatx4;

#define FXS 8388608.0f           // 2^23 fixed-point scale for degree accum
#define EA 320                   // coarse-count blocks
#define EPB 10000                // edges per coarse block (EA*EPB == E)
#define NBKT 391                 // dst>>8 buckets (100000>>8 = 390)

__device__ __forceinline__ unsigned short f2bf(float f) {
    unsigned u = __float_as_uint(f);
    u += 0x7fff + ((u >> 16) & 1);          // round-to-nearest-even
    return (unsigned short)(u >> 16);
}
__device__ __forceinline__ float bf2f(unsigned short s) {
    return __uint_as_float(((unsigned)s) << 16);
}
__device__ __forceinline__ float bflo(unsigned u) {
    return __uint_as_float(u << 16);
}
__device__ __forceinline__ float bfhi(unsigned u) {
    return __uint_as_float(u & 0xffff0000u);
}
__device__ __forceinline__ unsigned pack_bf2(float a, float b) {
    union { __hip_bfloat162 h2; unsigned u; } cv;
    cv.h2 = __float22bfloat162_rn(make_float2(a, b));   // v_cvt_pk_bf16_f32
    return cv.u;
}

// ------------------------------------------------------------------
// Setup: pack WcatT[192][512] / Wc1T / Wc2T / W2T (bf16, transposed)
// ------------------------------------------------------------------
__global__ void setup_misc(const float* __restrict__ W1, const float* __restrict__ b1,
                           const float* __restrict__ Ww, const float* __restrict__ bw,
                           const float* __restrict__ Wa, const float* __restrict__ ba,
                           const float* __restrict__ Wc1, const float* __restrict__ Wc2,
                           const float* __restrict__ W2,
                           unsigned short* __restrict__ WcatT, float* __restrict__ bcat,
                           unsigned short* __restrict__ Wc1T, unsigned short* __restrict__ Wc2T,
                           unsigned short* __restrict__ W2T) {
    int bid = blockIdx.x, tid = threadIdx.x;
    if (bid < 192) {
        int c = bid;
        for (int kk = tid; kk < 512; kk += 256) {
            float v;
            if (c < 128)      v = W1[kk * 128 + c];
            else if (c < 168) v = Ww[kk * 40 + (c - 128)];
            else if (c < 170) v = Wa[kk * 2 + (c - 168)];
            else              v = 0.f;
            WcatT[(size_t)c * 512 + kk] = f2bf(v);
        }
        if (tid == 0) {
            float b;
            if (c < 128)      b = b1[c];
            else if (c < 168) b = bw[c - 128];
            else if (c < 170) b = ba[c - 168];
            else              b = 0.f;
            bcat[c] = b;
        }
    } else if (bid < 320) {
        int c = bid - 192;
        if (tid < 128) Wc1T[(size_t)c * 128 + tid] = f2bf(Wc1[tid * 128 + c]);
        else { int k = tid - 128; Wc2T[(size_t)c * 128 + k] = f2bf(Wc2[k * 128 + c]); }
    } else {
        int c = bid - 320;                    // 0..63
        if (tid < 128)
            W2T[(size_t)c * 128 + tid] = (c < 40) ? f2bf(W2[tid * 40 + c])
                                                  : (unsigned short)0;
    }
}

// ------------------------------------------------------------------
// MFMA bf16 GEMM body: tile 64(M) x (32*NT)(N), K-step 32, 4 waves.
// Register-staged double buffer: K-step k+1's global loads are issued
// right after the first barrier of step k, hiding HBM latency under
// the MFMA + LDS reads of step k.
// EPI 0: C0 bf16 [M][128] = rowscale[m] * val
// EPI 1: n<128 -> relu+bias -> C0 bf16; n<168 -> C1 fp32; n<170 -> C2 fp32
// EPI 2: final fusion: C1=out, C2=wide, bias=b2, rowscale=attnL (2/row)
// ------------------------------------------------------------------
template <int EPI, int NT, int AF32>
__device__ __forceinline__ void gemm_body(
    int mblk, const void* __restrict__ Avoid, const unsigned short* __restrict__ BT,
    int M, int K,
    unsigned short* __restrict__ C0, float* __restrict__ C1, float* __restrict__ C2,
    const float* __restrict__ bias, const float* __restrict__ rowscale) {
    constexpr int NB = 32 * NT;
    constexpr int RB = NT / 2;                 // B-stage uint4 regs per thread
    __shared__ __align__(16) unsigned short Ast[64 * 40];
    __shared__ __align__(16) unsigned short Bst[NB * 40];

    int tid = threadIdx.x;
    int m0 = mblk * 64;
    int wave = tid >> 6, lane = tid & 63;
    int quad = lane >> 4, mi = lane & 15;
    int wm = (wave >> 1) * 32;
    int wn = (wave & 1) * (16 * NT);

    int srow = tid >> 2;
    int sk8 = (tid & 3) * 8;

    int arow = m0 + srow; if (arow >= M) arow = M - 1;

    // per-thread global source pointers (element units)
    const float* Afp = (const float*)Avoid + (size_t)arow * K + sk8;
    const unsigned short* Abp = (const unsigned short*)Avoid + (size_t)arow * K + sk8;
    int brow[RB], bk8[RB];
    const unsigned short* Bp[RB];
#pragma unroll
    for (int r = 0; r < RB; ++r) {
        int i = tid + r * 256;
        brow[r] = i >> 2;
        bk8[r] = (i & 3) * 8;
        Bp[r] = BT + (size_t)(i >> 2) * K + (i & 3) * 8;
    }

    // prefetch K-step 0
    float4 fA0, fA1; uint4 aR;
    if (AF32) { fA0 = *(const float4*)(Afp); fA1 = *(const float4*)(Afp + 4); }
    else      { aR = *(const uint4*)(Abp); }
    uint4 bR[RB];
#pragma unroll
    for (int r = 0; r < RB; ++r) bR[r] = *(const uint4*)(Bp[r]);

    floatx4 acc[2][NT] = {};

    for (int kc = 0; kc < K; kc += 32) {
        // commit staged regs to LDS
        if (AF32) {
            uint4 pk;
            pk.x = pack_bf2(fA0.x, fA0.y);
            pk.y = pack_bf2(fA0.z, fA0.w);
            pk.z = pack_bf2(fA1.x, fA1.y);
            pk.w = pack_bf2(fA1.z, fA1.w);
            *(uint4*)&Ast[srow * 40 + sk8] = pk;
        } else {
            *(uint4*)&Ast[srow * 40 + sk8] = aR;
        }
#pragma unroll
        for (int r = 0; r < RB; ++r)
            *(uint4*)&Bst[brow[r] * 40 + bk8[r]] = bR[r];
        __syncthreads();

        // issue next K-step's loads; latency hides under MFMA below
        if (kc + 32 < K) {
            if (AF32) {
                fA0 = *(const float4*)(Afp + kc + 32);
                fA1 = *(const float4*)(Afp + kc + 36);
            } else {
                aR = *(const uint4*)(Abp + kc + 32);
            }
#pragma unroll
            for (int r = 0; r < RB; ++r) bR[r] = *(const uint4*)(Bp[r] + kc + 32);
        }

        short8 a0 = *(const short8*)&Ast[(wm + mi) * 40 + quad * 8];
        short8 a1 = *(const short8*)&Ast[(wm + 16 + mi) * 40 + quad * 8];
#pragma unroll
        for (int nt = 0; nt < NT; ++nt) {
            short8 b = *(const short8*)&Bst[(wn + nt * 16 + mi) * 40 + quad * 8];
            acc[0][nt] = __builtin_amdgcn_mfma_f32_16x16x32_bf16(a0, b, acc[0][nt], 0, 0, 0);
            acc[1][nt] = __builtin_amdgcn_mfma_f32_16x16x32_bf16(a1, b, acc[1][nt], 0, 0, 0);
        }
        __syncthreads();
    }

#pragma unroll
    for (int mt = 0; mt < 2; ++mt) {
#pragma unroll
        for (int nt = 0; nt < NT; ++nt) {
            floatx4 v = acc[mt][nt];
            int gn = wn + nt * 16 + mi;
#pragma unroll
            for (int r = 0; r < 4; ++r) {
                int gm = m0 + wm + mt * 16 + quad * 4 + r;
                if (gm >= M) continue;
                float val = v[r];
                if (EPI == 0) {
                    C0[(size_t)gm * 128 + gn] = f2bf(rowscale[gm] * val);
                } else if (EPI == 1) {
                    val += bias[gn];
                    if (gn < 128)      C0[(size_t)gm * 128 + gn] = f2bf(fmaxf(val, 0.f));
                    else if (gn < 168) C1[(size_t)gm * 40 + (gn - 128)] = val;
                    else if (gn < 170) C2[(size_t)gm * 2 + (gn - 168)] = val;
                } else {
                    if (gn < 40) {
                        float l0 = rowscale[gm * 2], l1 = rowscale[gm * 2 + 1];
                        float mx = fmaxf(l0, l1);
                        float e0 = __expf(l0 - mx), e1 = __expf(l1 - mx);
                        float inv = 1.f / (e0 + e1);
                        C1[(size_t)gm * 40 + gn] =
                            (val + bias[gn]) * (e0 * inv) +
                            C2[(size_t)gm * 40 + gn] * (e1 * inv);
                    }
                }
            }
        }
    }
}

// ------------------------------------------------------------------
// megaA: bid < EA -> coarse histogram of dst>>8 into LDS, dump to
// histA[k*EA + bid] (plain stores, no global atomics).
// bid >= EA -> input GEMM (x -> h0/wide/attnL).
// ------------------------------------------------------------------
__global__ __launch_bounds__(256) void megaA(
    const float* __restrict__ x, const unsigned short* __restrict__ WcatT,
    unsigned short* __restrict__ h0, float* __restrict__ wide, float* __restrict__ attnL,
    const float* __restrict__ bcat, const int* __restrict__ ei,
    int* __restrict__ histA, int M, int e) {
    int bid = blockIdx.x;
    if (bid >= EA) {
        gemm_body<1, 6, 1>(bid - EA, x, WcatT, M, 512, h0, wide, attnL, bcat, nullptr);
        return;
    }
    __shared__ unsigned lh[NBKT];
    int tid = threadIdx.x;
    for (int i = tid; i < NBKT; i += 256) lh[i] = 0;
    __syncthreads();
    int base = bid * EPB, end = base + EPB; if (end > e) end = e;
    for (int i = base + tid; i < end; i += 256) {
        int d = ei[e + i];
        atomicAdd(&lh[d >> 8], 1u);
    }
    __syncthreads();
    for (int k = tid; k < NBKT; k += 256) histA[k * EA + bid] = (int)lh[k];
}

// ------------------------------------------------------------------
// scatterA: re-read edge range, rank within (bucket, block) via LDS
// fetch-add, scatter (src | dlow<<24, w) into coarse-sorted cs[].
// ------------------------------------------------------------------
__global__ __launch_bounds__(256) void scatterA(
    const int* __restrict__ ei, const float* __restrict__ ew,
    const int* __restrict__ offA, uint2* __restrict__ cs, int e) {
    int bid = blockIdx.x, tid = threadIdx.x;
    __shared__ unsigned lh[NBKT];
    __shared__ int lo[NBKT];
    for (int i = tid; i < NBKT; i += 256) { lh[i] = 0; lo[i] = offA[i * EA + bid]; }
    __syncthreads();
    int base = bid * EPB, end = base + EPB; if (end > e) end = e;
    for (int i = base + tid; i < end; i += 256) {
        int d = ei[e + i];
        int r = ei[i];
        float w = ew[i];
        int k = d >> 8;
        unsigned lr = atomicAdd(&lh[k], 1u);
        cs[lo[k] + (int)lr] = make_uint2((unsigned)r | ((unsigned)(d & 255) << 24),
                                         __float_as_uint(w));
    }
}

// ------------------------------------------------------------------
// passB1: one block per bucket; fine counts + fixed-point weight sums,
// then intra-bucket exclusive scan. Bucket's global edge base is
// offA[k*EA], so ptr[] and dinv[] are produced directly — no global
// scan over per-dst counts needed.
// ------------------------------------------------------------------
__global__ __launch_bounds__(1024) void passB1(
    const uint2* __restrict__ cs, const int* __restrict__ offA,
    int* __restrict__ ptr, float* __restrict__ dinv, int n, int e) {
    int k = blockIdx.x, tid = threadIdx.x;
    __shared__ unsigned lc[256], lw[256];
    __shared__ int ls[256];
    if (tid < 256) { lc[tid] = 0; lw[tid] = 0; }
    __syncthreads();
    int start = offA[k * EA];
    int end = (k == NBKT - 1) ? e : offA[(k + 1) * EA];
    for (int i = start + tid; i < end; i += 1024) {
        uint2 u = cs[i];
        int dlow = u.x >> 24;
        unsigned fx = (unsigned)(__uint_as_float(u.y) * FXS);
        atomicAdd(&lc[dlow], 1u);
        atomicAdd(&lw[dlow], fx);
    }
    __syncthreads();
    int v = (tid < 256) ? (int)lc[tid] : 0;
    if (tid < 256) ls[tid] = v;
    __syncthreads();
    for (int off = 1; off < 256; off <<= 1) {
        int t = (tid < 256 && tid >= off) ? ls[tid - off] : 0;
        __syncthreads();
        if (tid < 256) ls[tid] += t;
        __syncthreads();
    }
    if (tid < 256) {
        int d = (k << 8) + tid;
        if (d < n) {
            ptr[d]  = start + ls[tid] - v;       // exclusive
            dinv[d] = rsqrtf(1.0f + (float)lw[tid] * (1.0f / FXS));
        }
    }
    if (k == NBKT - 1 && tid == 0) ptr[n] = e;
}

// ------------------------------------------------------------------
// megaB: bid < NBKT -> fine scatter (CSR fill) via LDS ranks, writes go
// into the contiguous per-bucket region of edges[].
// bid >= NBKT -> conv1 GEMM (h0 -> tmpB, dinv rowscale).
// ------------------------------------------------------------------
__global__ __launch_bounds__(256) void megaB(
    const unsigned short* __restrict__ h0, const unsigned short* __restrict__ Wc1T,
    unsigned short* __restrict__ tmpB, const float* __restrict__ dinv,
    const uint2* __restrict__ cs, const int* __restrict__ offA,
    const int* __restrict__ ptr, uint2* __restrict__ edges, int M, int n, int e) {
    int bid = blockIdx.x;
    if (bid >= NBKT) {
        gemm_body<0, 4, 0>(bid - NBKT, h0, Wc1T, M, 128, tmpB, nullptr, nullptr, nullptr, dinv);
        return;
    }
    int k = bid, tid = threadIdx.x;
    __shared__ unsigned lc[256];
    __shared__ int lp[256];
    { lc[tid] = 0; int d = (k << 8) + tid; lp[tid] = (d < n) ? ptr[d] : 0; }
    __syncthreads();
    int start = offA[k * EA];
    int end = (k == NBKT - 1) ? e : offA[(k + 1) * EA];
    for (int i = start + tid; i < end; i += 256) {
        uint2 u = cs[i];
        int dlow = u.x >> 24;
        unsigned src = u.x & 0x00FFFFFFu;
        unsigned lr = atomicAdd(&lc[dlow], 1u);
        edges[lp[dlow] + (int)lr] = make_uint2(src, u.y);
    }
}

__global__ __launch_bounds__(256) void gemm_conv(
    const unsigned short* __restrict__ A, const unsigned short* __restrict__ BT,
    unsigned short* __restrict__ C0, const float* __restrict__ rowscale, int M) {
    gemm_body<0, 4, 0>(blockIdx.x, A, BT, M, 128, C0, nullptr, nullptr, nullptr, rowscale);
}

// ------------------------------------------------------------------
// Final layer as MFMA GEMM: out = (h2 @ W2 + b2)*a0 + wide*a1
// ------------------------------------------------------------------
__global__ __launch_bounds__(256) void gemm_final(
    const unsigned short* __restrict__ A, const unsigned short* __restrict__ W2T,
    float* __restrict__ out, float* __restrict__ wide,
    const float* __restrict__ attnL, const float* __restrict__ b2, int M) {
    gemm_body<2, 2, 0>(blockIdx.x, A, W2T, M, 128, nullptr, out, wide, b2, attnL);
}

// ------------------------------------------------------------------
// Generic int exclusive scan (1024-wide blocks + block-sum fixup).
// Used only for the histA (bucket,block) offset table now.
// ------------------------------------------------------------------
__global__ void scan1(const int* __restrict__ in, int* __restrict__ out,
                      int* __restrict__ bsum, int n) {
    __shared__ int s[1024];
    int tid = threadIdx.x;
    int i = blockIdx.x * 1024 + tid;
    int v = (i < n) ? in[i] : 0;
    s[tid] = v;
    __syncthreads();
    for (int off = 1; off < 1024; off <<= 1) {
        int t = (tid >= off) ? s[tid - off] : 0;
        __syncthreads();
        s[tid] += t;
        __syncthreads();
    }
    if (i < n) out[i] = s[tid] - v;              // exclusive
    if (tid == 1023) bsum[blockIdx.x] = s[1023];
}

__global__ void scan_bsums(int* bsum, int nb) {
    __shared__ int s[1024];
    int tid = threadIdx.x;
    int v = (tid < nb) ? bsum[tid] : 0;
    s[tid] = v;
    __syncthreads();
    for (int off = 1; off < 1024; off <<= 1) {
        int t = (tid >= off) ? s[tid - off] : 0;
        __syncthreads();
        s[tid] += t;
        __syncthreads();
    }
    if (tid < nb) bsum[tid] = s[tid] - v;        // exclusive
}

__global__ void scan_add(int* __restrict__ out, const int* __restrict__ bsum,
                         int n, int tailv) {
    int i = blockIdx.x * 1024 + threadIdx.x;
    if (i < n) out[i] += bsum[blockIdx.x];
    if (i == 0 && tailv >= 0) out[n] = tailv;
}

// ------------------------------------------------------------------
// GCN propagation, dst-CSR, bf16 messages, dinv pre-folded into rows:
// out[d] = relu(dinv[d] * (tmp'[d] + sum ew*tmp'[src]) + bias)
// One WAVE per dst node, 8-deep edge unroll for MLP.
// ------------------------------------------------------------------
__global__ __launch_bounds__(256) void propagate(
    const unsigned int* __restrict__ tmp2,    // [M][64] packed bf16x2 (dinv-scaled)
    unsigned int* __restrict__ out2,
    const float* __restrict__ bias, const float* __restrict__ dinv,
    const int* __restrict__ ptr, const uint2* __restrict__ edges, int n) {
    int wave = threadIdx.x >> 6, lane = threadIdx.x & 63;
    int d = blockIdx.x * 4 + wave;
    if (d >= n) return;

    unsigned u = tmp2[(size_t)d * 64 + lane];   // self loop
    float acc0 = bflo(u);
    float acc1 = bfhi(u);

    int p = ptr[d], p1 = ptr[d + 1];
    for (; p + 8 <= p1; p += 8) {
        uint2 q[8];
#pragma unroll
        for (int j = 0; j < 8; ++j) q[j] = edges[p + j];
        unsigned rv[8];
#pragma unroll
        for (int j = 0; j < 8; ++j) rv[j] = tmp2[(size_t)q[j].x * 64 + lane];
#pragma unroll
        for (int j = 0; j < 8; ++j) {
            float w = __uint_as_float(q[j].y);
            acc0 += w * bflo(rv[j]); acc1 += w * bfhi(rv[j]);
        }
    }
    for (; p < p1; ++p) {
        uint2 q = edges[p];
        unsigned a = tmp2[(size_t)q.x * 64 + lane];
        float w = __uint_as_float(q.y);
        acc0 += w * bflo(a); acc1 += w * bfhi(a);
    }
    float di = dinv[d];
    float v0 = fmaxf(di * acc0 + bias[2 * lane], 0.f);
    float v1 = fmaxf(di * acc1 + bias[2 * lane + 1], 0.f);
    out2[(size_t)d * 64 + lane] = (unsigned)f2bf(v0) | ((unsigned)f2bf(v1) << 16);
}

// ------------------------------------------------------------------
extern "C" void kernel_launch(void* const* d_in, const int* in_sizes, int n_in,
                              void* d_out, int out_size, void* d_ws, size_t ws_size,
                              hipStream_t stream) {
    (void)in_sizes; (void)n_in; (void)out_size; (void)ws_size;
    const float* x   = (const float*)d_in[0];
    const int*   ei  = (const int*)d_in[1];
    const float* ew  = (const float*)d_in[2];
    const float* W1  = (const float*)d_in[3];
    const float* b1  = (const float*)d_in[4];
    const float* Wc1 = (const float*)d_in[5];
    const float* bc1 = (const float*)d_in[6];
    const float* Wc2 = (const float*)d_in[7];
    const float* bc2 = (const float*)d_in[8];
    const float* W2  = (const float*)d_in[9];
    const float* b2  = (const float*)d_in[10];
    const float* Ww  = (const float*)d_in[11];
    const float* bw  = (const float*)d_in[12];
    const float* Wa  = (const float*)d_in[13];
    const float* ba  = (const float*)d_in[14];
    float* out = (float*)d_out;

    const int N = N_NODES, E = N_EDGES;
    char* ws = (char*)d_ws;
    size_t off = 0;
    auto alloc = [&](size_t bytes) -> void* {
        void* p = ws + off;
        off = (off + bytes + 255) & ~(size_t)255;
        return p;
    };
    unsigned short* bufA = (unsigned short*)alloc((size_t)N * 128 * 2);
    unsigned short* bufB = (unsigned short*)alloc((size_t)N * 128 * 2);
    float* wide  = (float*)alloc((size_t)N * 40 * 4);
    float* attnL = (float*)alloc((size_t)N * 2 * 4);
    float* dinv  = (float*)alloc((size_t)N * 4);
    int*   histA = (int*)alloc((size_t)NBKT * EA * 4);   // scanned in place -> offA
    uint2* cs    = (uint2*)alloc((size_t)E * 8);         // coarse bucket-sorted records
    int*   ptr   = (int*)alloc((size_t)(N + 1) * 4);
    int*   bsum  = (int*)alloc(1024 * 4);
    uint2* edges = (uint2*)alloc((size_t)E * 8);
    unsigned short* WcatT = (unsigned short*)alloc((size_t)192 * 512 * 2);
    unsigned short* Wc1T  = (unsigned short*)alloc((size_t)128 * 128 * 2);
    unsigned short* Wc2T  = (unsigned short*)alloc((size_t)128 * 128 * 2);
    unsigned short* W2T   = (unsigned short*)alloc((size_t)64 * 128 * 2);
    float* bcat  = (float*)alloc(192 * 4);

    const int MB = (N + 63) / 64;          // 1563 gemm m-blocks
    const int NHA = NBKT * EA;             // 125120 histogram entries

    // setup: weight packs
    setup_misc<<<384, 256, 0, stream>>>(W1, b1, Ww, bw, Wa, ba, Wc1, Wc2, W2,
                                        WcatT, bcat, Wc1T, Wc2T, W2T);

    // megaA: input GEMM overlapped with coarse dst-histogram (LDS only)
    megaA<<<EA + MB, 256, 0, stream>>>(x, WcatT, bufA, wide, attnL, bcat,
                                       ei, histA, N, E);

    // scan histA (bucket-major) -> per-(bucket,block) bases, in place
    int nbA = (NHA + 1023) / 1024;
    scan1<<<nbA, 1024, 0, stream>>>(histA, histA, bsum, NHA);
    scan_bsums<<<1, 1024, 0, stream>>>(bsum, nbA);
    scan_add<<<nbA, 1024, 0, stream>>>(histA, bsum, NHA, -1);

    // coarse scatter into cs[]
    scatterA<<<EA, 256, 0, stream>>>(ei, ew, histA, cs, E);

    // fine counts + weight sums per dst -> ptr[] + dinv[] directly
    passB1<<<NBKT, 1024, 0, stream>>>(cs, histA, ptr, dinv, N, E);

    // megaB: conv1 GEMM (h0 -> tmpB, dinv-scaled) overlapped with CSR fill
    megaB<<<NBKT + MB, 256, 0, stream>>>(bufA, Wc1T, bufB, dinv,
                                         cs, histA, ptr, edges, N, N, E);
    propagate<<<(N + 3) / 4, 256, 0, stream>>>((const unsigned int*)bufB, (unsigned int*)bufA,
                                               bc1, dinv, ptr, edges, N);

    // conv layer 2
    gemm_conv<<<MB, 256, 0, stream>>>(bufA, Wc2T, bufB, dinv, N);
    propagate<<<(N + 3) / 4, 256, 0, stream>>>((const unsigned int*)bufB, (unsigned int*)bufA,
                                               bc2, dinv, ptr, edges, N);

    // final fusion: MFMA GEMM replaces scalar final_k
    gemm_final<<<MB, 256, 0, stream>>>(bufA, W2T, out, wide, attnL, b2, N);
}

// Round 5
// 781.215 us; speedup vs baseline: 1.0749x; 1.0749x over previous
//
#include <hip/hip_runtime.h>
#include <hip/hip_bf16.h>
#include <cstdint>

#define N_NODES 100000
#define N_EDGES 3200000

typedef __attribute__((ext_vector_type(8))) short short8;
typedef __attribute__((ext_vector_type(4))) float floatx4;

#define FXS 8388608.0f           // 2^23 fixed-point scale for degree accum
#define EA 320                   // coarse-count blocks
#define EPB 10000                // edges per coarse block (EA*EPB == E)
#define NBKT 391                 // dst>>8 buckets (100000>>8 = 390)

__device__ __forceinline__ unsigned short f2bf(float f) {
    unsigned u = __float_as_uint(f);
    u += 0x7fff + ((u >> 16) & 1);          // round-to-nearest-even
    return (unsigned short)(u >> 16);
}
__device__ __forceinline__ float bf2f(unsigned short s) {
    return __uint_as_float(((unsigned)s) << 16);
}
__device__ __forceinline__ float bflo(unsigned u) {
    return __uint_as_float(u << 16);
}
__device__ __forceinline__ float bfhi(unsigned u) {
    return __uint_as_float(u & 0xffff0000u);
}
__device__ __forceinline__ unsigned pack_bf2(float a, float b) {
    union { __hip_bfloat162 h2; unsigned u; } cv;
    cv.h2 = __float22bfloat162_rn(make_float2(a, b));   // v_cvt_pk_bf16_f32
    return cv.u;
}

// ------------------------------------------------------------------
// Setup: pack WcatT[192][512] / Wc1T / Wc2T / W2T (bf16, transposed)
// ------------------------------------------------------------------
__global__ void setup_misc(const float* __restrict__ W1, const float* __restrict__ b1,
                           const float* __restrict__ Ww, const float* __restrict__ bw,
                           const float* __restrict__ Wa, const float* __restrict__ ba,
                           const float* __restrict__ Wc1, const float* __restrict__ Wc2,
                           const float* __restrict__ W2,
                           unsigned short* __restrict__ WcatT, float* __restrict__ bcat,
                           unsigned short* __restrict__ Wc1T, unsigned short* __restrict__ Wc2T,
                           unsigned short* __restrict__ W2T) {
    int bid = blockIdx.x, tid = threadIdx.x;
    if (bid < 192) {
        int c = bid;
        for (int kk = tid; kk < 512; kk += 256) {
            float v;
            if (c < 128)      v = W1[kk * 128 + c];
            else if (c < 168) v = Ww[kk * 40 + (c - 128)];
            else if (c < 170) v = Wa[kk * 2 + (c - 168)];
            else              v = 0.f;
            WcatT[(size_t)c * 512 + kk] = f2bf(v);
        }
        if (tid == 0) {
            float b;
            if (c < 128)      b = b1[c];
            else if (c < 168) b = bw[c - 128];
            else if (c < 170) b = ba[c - 168];
            else              b = 0.f;
            bcat[c] = b;
        }
    } else if (bid < 320) {
        int c = bid - 192;
        if (tid < 128) Wc1T[(size_t)c * 128 + tid] = f2bf(Wc1[tid * 128 + c]);
        else { int k = tid - 128; Wc2T[(size_t)c * 128 + k] = f2bf(Wc2[k * 128 + c]); }
    } else {
        int c = bid - 320;                    // 0..63
        if (tid < 128)
            W2T[(size_t)c * 128 + tid] = (c < 40) ? f2bf(W2[tid * 40 + c])
                                                  : (unsigned short)0;
    }
}

// ------------------------------------------------------------------
// MFMA bf16 GEMM body: tile 64(M) x (32*NT)(N), K-step 32, 4 waves.
// A: LDS double-buffer, ONE barrier per K-step (read cur / write nxt).
// B: direct per-wave global loads (weights are L2-resident; no LDS,
//    no long-lived staging regs -> no spills).
// EPI 0: C0 bf16 [M][128] = rowscale[m] * val
// EPI 1: n<128 -> relu+bias -> C0 bf16; n<168 -> C1 fp32; n<170 -> C2 fp32
// EPI 2: final fusion: C1=out, C2=wide, bias=b2, rowscale=attnL (2/row)
// ------------------------------------------------------------------
template <int EPI, int NT, int AF32>
__device__ __forceinline__ void gemm_body(
    int mblk, const void* __restrict__ Avoid, const unsigned short* __restrict__ BT,
    int M, int K,
    unsigned short* __restrict__ C0, float* __restrict__ C1, float* __restrict__ C2,
    const float* __restrict__ bias, const float* __restrict__ rowscale) {
    __shared__ __align__(16) unsigned short Ast[2][64 * 40];

    int tid = threadIdx.x;
    int m0 = mblk * 64;
    int wave = tid >> 6, lane = tid & 63;
    int quad = lane >> 4, mi = lane & 15;
    int wm = (wave >> 1) * 32;
    int wn = (wave & 1) * (16 * NT);

    int srow = tid >> 2;          // 0..63
    int sk8 = (tid & 3) * 8;      // 0,8,16,24

    int arow = m0 + srow; if (arow >= M) arow = M - 1;

    const float* Afp = (const float*)Avoid + (size_t)arow * K + sk8;
    const unsigned short* Abp = (const unsigned short*)Avoid + (size_t)arow * K + sk8;
    // per-wave B fragment base: row (wn + mi), col quad*8; nt adds 16 rows
    const unsigned short* Bfp = BT + (size_t)(wn + mi) * K + quad * 8;

    // stage K-step 0 into Ast[0]
    {
        if (AF32) {
            float4 f0 = *(const float4*)(Afp);
            float4 f1 = *(const float4*)(Afp + 4);
            uint4 pk;
            pk.x = pack_bf2(f0.x, f0.y); pk.y = pack_bf2(f0.z, f0.w);
            pk.z = pack_bf2(f1.x, f1.y); pk.w = pack_bf2(f1.z, f1.w);
            *(uint4*)&Ast[0][srow * 40 + sk8] = pk;
        } else {
            *(uint4*)&Ast[0][srow * 40 + sk8] = *(const uint4*)(Abp);
        }
    }
    __syncthreads();

    floatx4 acc[2][NT] = {};

    int cur = 0;
    for (int kc = 0; kc < K; kc += 32) {
        bool more = (kc + 32 < K);
        // issue next A-step global loads early: latency hides under MFMAs
        float4 fA0, fA1; uint4 aR;
        if (more) {
            if (AF32) {
                fA0 = *(const float4*)(Afp + kc + 32);
                fA1 = *(const float4*)(Afp + kc + 36);
            } else {
                aR = *(const uint4*)(Abp + kc + 32);
            }
        }
        // B fragments direct from global (L2-resident weights)
        uint4 bv[NT];
#pragma unroll
        for (int nt = 0; nt < NT; ++nt)
            bv[nt] = *(const uint4*)(Bfp + (size_t)nt * 16 * K + kc);

        short8 a0 = *(const short8*)&Ast[cur][(wm + mi) * 40 + quad * 8];
        short8 a1 = *(const short8*)&Ast[cur][(wm + 16 + mi) * 40 + quad * 8];
#pragma unroll
        for (int nt = 0; nt < NT; ++nt) {
            short8 b = *(const short8*)&bv[nt];
            acc[0][nt] = __builtin_amdgcn_mfma_f32_16x16x32_bf16(a0, b, acc[0][nt], 0, 0, 0);
            acc[1][nt] = __builtin_amdgcn_mfma_f32_16x16x32_bf16(a1, b, acc[1][nt], 0, 0, 0);
        }
        if (more) {
            if (AF32) {
                uint4 pk;
                pk.x = pack_bf2(fA0.x, fA0.y); pk.y = pack_bf2(fA0.z, fA0.w);
                pk.z = pack_bf2(fA1.x, fA1.y); pk.w = pack_bf2(fA1.z, fA1.w);
                *(uint4*)&Ast[cur ^ 1][srow * 40 + sk8] = pk;
            } else {
                *(uint4*)&Ast[cur ^ 1][srow * 40 + sk8] = aR;
            }
            __syncthreads();
            cur ^= 1;
        }
    }

#pragma unroll
    for (int mt = 0; mt < 2; ++mt) {
#pragma unroll
        for (int nt = 0; nt < NT; ++nt) {
            floatx4 v = acc[mt][nt];
            int gn = wn + nt * 16 + mi;
#pragma unroll
            for (int r = 0; r < 4; ++r) {
                int gm = m0 + wm + mt * 16 + quad * 4 + r;
                if (gm >= M) continue;
                float val = v[r];
                if (EPI == 0) {
                    C0[(size_t)gm * 128 + gn] = f2bf(rowscale[gm] * val);
                } else if (EPI == 1) {
                    val += bias[gn];
                    if (gn < 128)      C0[(size_t)gm * 128 + gn] = f2bf(fmaxf(val, 0.f));
                    else if (gn < 168) C1[(size_t)gm * 40 + (gn - 128)] = val;
                    else if (gn < 170) C2[(size_t)gm * 2 + (gn - 168)] = val;
                } else {
                    if (gn < 40) {
                        float l0 = rowscale[gm * 2], l1 = rowscale[gm * 2 + 1];
                        float mx = fmaxf(l0, l1);
                        float e0 = __expf(l0 - mx), e1 = __expf(l1 - mx);
                        float inv = 1.f / (e0 + e1);
                        C1[(size_t)gm * 40 + gn] =
                            (val + bias[gn]) * (e0 * inv) +
                            C2[(size_t)gm * 40 + gn] * (e1 * inv);
                    }
                }
            }
        }
    }
}

// ------------------------------------------------------------------
// megaA: bid < EA -> coarse histogram of dst>>8 into LDS, dump to
// histA[k*EA + bid] (plain stores, no global atomics).
// bid >= EA -> input GEMM (x -> h0/wide/attnL).
// ------------------------------------------------------------------
__global__ __launch_bounds__(256) void megaA(
    const float* __restrict__ x, const unsigned short* __restrict__ WcatT,
    unsigned short* __restrict__ h0, float* __restrict__ wide, float* __restrict__ attnL,
    const float* __restrict__ bcat, const int* __restrict__ ei,
    int* __restrict__ histA, int M, int e) {
    int bid = blockIdx.x;
    if (bid >= EA) {
        gemm_body<1, 6, 1>(bid - EA, x, WcatT, M, 512, h0, wide, attnL, bcat, nullptr);
        return;
    }
    __shared__ unsigned lh[NBKT];
    int tid = threadIdx.x;
    for (int i = tid; i < NBKT; i += 256) lh[i] = 0;
    __syncthreads();
    int base = bid * EPB, end = base + EPB; if (end > e) end = e;
    for (int i = base + tid; i < end; i += 256) {
        int d = ei[e + i];
        atomicAdd(&lh[d >> 8], 1u);
    }
    __syncthreads();
    for (int k = tid; k < NBKT; k += 256) histA[k * EA + bid] = (int)lh[k];
}

// ------------------------------------------------------------------
// scatterA: re-read edge range, rank within (bucket, block) via LDS
// fetch-add, scatter (src | dlow<<24, w) into coarse-sorted cs[].
// ------------------------------------------------------------------
__global__ __launch_bounds__(256) void scatterA(
    const int* __restrict__ ei, const float* __restrict__ ew,
    const int* __restrict__ offA, uint2* __restrict__ cs, int e) {
    int bid = blockIdx.x, tid = threadIdx.x;
    __shared__ unsigned lh[NBKT];
    __shared__ int lo[NBKT];
    for (int i = tid; i < NBKT; i += 256) { lh[i] = 0; lo[i] = offA[i * EA + bid]; }
    __syncthreads();
    int base = bid * EPB, end = base + EPB; if (end > e) end = e;
    for (int i = base + tid; i < end; i += 256) {
        int d = ei[e + i];
        int r = ei[i];
        float w = ew[i];
        int k = d >> 8;
        unsigned lr = atomicAdd(&lh[k], 1u);
        cs[lo[k] + (int)lr] = make_uint2((unsigned)r | ((unsigned)(d & 255) << 24),
                                         __float_as_uint(w));
    }
}

// ------------------------------------------------------------------
// passB1: one block per bucket; fine counts + fixed-point weight sums,
// then intra-bucket exclusive scan -> ptr[] and dinv[] directly.
// ------------------------------------------------------------------
__global__ __launch_bounds__(1024) void passB1(
    const uint2* __restrict__ cs, const int* __restrict__ offA,
    int* __restrict__ ptr, float* __restrict__ dinv, int n, int e) {
    int k = blockIdx.x, tid = threadIdx.x;
    __shared__ unsigned lc[256], lw[256];
    __shared__ int ls[256];
    if (tid < 256) { lc[tid] = 0; lw[tid] = 0; }
    __syncthreads();
    int start = offA[k * EA];
    int end = (k == NBKT - 1) ? e : offA[(k + 1) * EA];
    for (int i = start + tid; i < end; i += 1024) {
        uint2 u = cs[i];
        int dlow = u.x >> 24;
        unsigned fx = (unsigned)(__uint_as_float(u.y) * FXS);
        atomicAdd(&lc[dlow], 1u);
        atomicAdd(&lw[dlow], fx);
    }
    __syncthreads();
    int v = (tid < 256) ? (int)lc[tid] : 0;
    if (tid < 256) ls[tid] = v;
    __syncthreads();
    for (int off = 1; off < 256; off <<= 1) {
        int t = (tid < 256 && tid >= off) ? ls[tid - off] : 0;
        __syncthreads();
        if (tid < 256) ls[tid] += t;
        __syncthreads();
    }
    if (tid < 256) {
        int d = (k << 8) + tid;
        if (d < n) {
            ptr[d]  = start + ls[tid] - v;       // exclusive
            dinv[d] = rsqrtf(1.0f + (float)lw[tid] * (1.0f / FXS));
        }
    }
    if (k == NBKT - 1 && tid == 0) ptr[n] = e;
}

// ------------------------------------------------------------------
// megaB: bid < NBKT -> fine scatter (CSR fill) via LDS ranks, writes go
// into the contiguous per-bucket region of edges[].
// bid >= NBKT -> conv1 GEMM (h0 -> tmpB, dinv rowscale).
// ------------------------------------------------------------------
__global__ __launch_bounds__(256) void megaB(
    const unsigned short* __restrict__ h0, const unsigned short* __restrict__ Wc1T,
    unsigned short* __restrict__ tmpB, const float* __restrict__ dinv,
    const uint2* __restrict__ cs, const int* __restrict__ offA,
    const int* __restrict__ ptr, uint2* __restrict__ edges, int M, int n, int e) {
    int bid = blockIdx.x;
    if (bid >= NBKT) {
        gemm_body<0, 4, 0>(bid - NBKT, h0, Wc1T, M, 128, tmpB, nullptr, nullptr, nullptr, dinv);
        return;
    }
    int k = bid, tid = threadIdx.x;
    __shared__ unsigned lc[256];
    __shared__ int lp[256];
    { lc[tid] = 0; int d = (k << 8) + tid; lp[tid] = (d < n) ? ptr[d] : 0; }
    __syncthreads();
    int start = offA[k * EA];
    int end = (k == NBKT - 1) ? e : offA[(k + 1) * EA];
    for (int i = start + tid; i < end; i += 256) {
        uint2 u = cs[i];
        int dlow = u.x >> 24;
        unsigned src = u.x & 0x00FFFFFFu;
        unsigned lr = atomicAdd(&lc[dlow], 1u);
        edges[lp[dlow] + (int)lr] = make_uint2(src, u.y);
    }
}

__global__ __launch_bounds__(256) void gemm_conv(
    const unsigned short* __restrict__ A, const unsigned short* __restrict__ BT,
    unsigned short* __restrict__ C0, const float* __restrict__ rowscale, int M) {
    gemm_body<0, 4, 0>(blockIdx.x, A, BT, M, 128, C0, nullptr, nullptr, nullptr, rowscale);
}

// ------------------------------------------------------------------
// Final layer as MFMA GEMM: out = (h2 @ W2 + b2)*a0 + wide*a1
// ------------------------------------------------------------------
__global__ __launch_bounds__(256) void gemm_final(
    const unsigned short* __restrict__ A, const unsigned short* __restrict__ W2T,
    float* __restrict__ out, float* __restrict__ wide,
    const float* __restrict__ attnL, const float* __restrict__ b2, int M) {
    gemm_body<2, 2, 0>(blockIdx.x, A, W2T, M, 128, nullptr, out, wide, b2, attnL);
}

// ------------------------------------------------------------------
// Generic int exclusive scan (1024-wide blocks + block-sum fixup).
// Used only for the histA (bucket,block) offset table.
// ------------------------------------------------------------------
__global__ void scan1(const int* __restrict__ in, int* __restrict__ out,
                      int* __restrict__ bsum, int n) {
    __shared__ int s[1024];
    int tid = threadIdx.x;
    int i = blockIdx.x * 1024 + tid;
    int v = (i < n) ? in[i] : 0;
    s[tid] = v;
    __syncthreads();
    for (int off = 1; off < 1024; off <<= 1) {
        int t = (tid >= off) ? s[tid - off] : 0;
        __syncthreads();
        s[tid] += t;
        __syncthreads();
    }
    if (i < n) out[i] = s[tid] - v;              // exclusive
    if (tid == 1023) bsum[blockIdx.x] = s[1023];
}

__global__ void scan_bsums(int* bsum, int nb) {
    __shared__ int s[1024];
    int tid = threadIdx.x;
    int v = (tid < nb) ? bsum[tid] : 0;
    s[tid] = v;
    __syncthreads();
    for (int off = 1; off < 1024; off <<= 1) {
        int t = (tid >= off) ? s[tid - off] : 0;
        __syncthreads();
        s[tid] += t;
        __syncthreads();
    }
    if (tid < nb) bsum[tid] = s[tid] - v;        // exclusive
}

__global__ void scan_add(int* __restrict__ out, const int* __restrict__ bsum,
                         int n, int tailv) {
    int i = blockIdx.x * 1024 + threadIdx.x;
    if (i < n) out[i] += bsum[blockIdx.x];
    if (i == 0 && tailv >= 0) out[n] = tailv;
}

// ------------------------------------------------------------------
// GCN propagation, dst-CSR, bf16 messages, dinv pre-folded into rows:
// out[d] = relu(dinv[d] * (tmp'[d] + sum ew*tmp'[src]) + bias)
// One WAVE per dst node, 8-deep edge unroll for MLP.
// ------------------------------------------------------------------
__global__ __launch_bounds__(256) void propagate(
    const unsigned int* __restrict__ tmp2,    // [M][64] packed bf16x2 (dinv-scaled)
    unsigned int* __restrict__ out2,
    const float* __restrict__ bias, const float* __restrict__ dinv,
    const int* __restrict__ ptr, const uint2* __restrict__ edges, int n) {
    int wave = threadIdx.x >> 6, lane = threadIdx.x & 63;
    int d = blockIdx.x * 4 + wave;
    if (d >= n) return;

    unsigned u = tmp2[(size_t)d * 64 + lane];   // self loop
    float acc0 = bflo(u);
    float acc1 = bfhi(u);

    int p = ptr[d], p1 = ptr[d + 1];
    for (; p + 8 <= p1; p += 8) {
        uint2 q[8];
#pragma unroll
        for (int j = 0; j < 8; ++j) q[j] = edges[p + j];
        unsigned rv[8];
#pragma unroll
        for (int j = 0; j < 8; ++j) rv[j] = tmp2[(size_t)q[j].x * 64 + lane];
#pragma unroll
        for (int j = 0; j < 8; ++j) {
            float w = __uint_as_float(q[j].y);
            acc0 += w * bflo(rv[j]); acc1 += w * bfhi(rv[j]);
        }
    }
    for (; p < p1; ++p) {
        uint2 q = edges[p];
        unsigned a = tmp2[(size_t)q.x * 64 + lane];
        float w = __uint_as_float(q.y);
        acc0 += w * bflo(a); acc1 += w * bfhi(a);
    }
    float di = dinv[d];
    float v0 = fmaxf(di * acc0 + bias[2 * lane], 0.f);
    float v1 = fmaxf(di * acc1 + bias[2 * lane + 1], 0.f);
    out2[(size_t)d * 64 + lane] = (unsigned)f2bf(v0) | ((unsigned)f2bf(v1) << 16);
}

// ------------------------------------------------------------------
extern "C" void kernel_launch(void* const* d_in, const int* in_sizes, int n_in,
                              void* d_out, int out_size, void* d_ws, size_t ws_size,
                              hipStream_t stream) {
    (void)in_sizes; (void)n_in; (void)out_size; (void)ws_size;
    const float* x   = (const float*)d_in[0];
    const int*   ei  = (const int*)d_in[1];
    const float* ew  = (const float*)d_in[2];
    const float* W1  = (const float*)d_in[3];
    const float* b1  = (const float*)d_in[4];
    const float* Wc1 = (const float*)d_in[5];
    const float* bc1 = (const float*)d_in[6];
    const float* Wc2 = (const float*)d_in[7];
    const float* bc2 = (const float*)d_in[8];
    const float* W2  = (const float*)d_in[9];
    const float* b2  = (const float*)d_in[10];
    const float* Ww  = (const float*)d_in[11];
    const float* bw  = (const float*)d_in[12];
    const float* Wa  = (const float*)d_in[13];
    const float* ba  = (const float*)d_in[14];
    float* out = (float*)d_out;

    const int N = N_NODES, E = N_EDGES;
    char* ws = (char*)d_ws;
    size_t off = 0;
    auto alloc = [&](size_t bytes) -> void* {
        void* p = ws + off;
        off = (off + bytes + 255) & ~(size_t)255;
        return p;
    };
    unsigned short* bufA = (unsigned short*)alloc((size_t)N * 128 * 2);
    unsigned short* bufB = (unsigned short*)alloc((size_t)N * 128 * 2);
    float* wide  = (float*)alloc((size_t)N * 40 * 4);
    float* attnL = (float*)alloc((size_t)N * 2 * 4);
    float* dinv  = (float*)alloc((size_t)N * 4);
    int*   histA = (int*)alloc((size_t)NBKT * EA * 4);   // scanned in place -> offA
    uint2* cs    = (uint2*)alloc((size_t)E * 8);         // coarse bucket-sorted records
    int*   ptr   = (int*)alloc((size_t)(N + 1) * 4);
    int*   bsum  = (int*)alloc(1024 * 4);
    uint2* edges = (uint2*)alloc((size_t)E * 8);
    unsigned short* WcatT = (unsigned short*)alloc((size_t)192 * 512 * 2);
    unsigned short* Wc1T  = (unsigned short*)alloc((size_t)128 * 128 * 2);
    unsigned short* Wc2T  = (unsigned short*)alloc((size_t)128 * 128 * 2);
    unsigned short* W2T   = (unsigned short*)alloc((size_t)64 * 128 * 2);
    float* bcat  = (float*)alloc(192 * 4);

    const int MB = (N + 63) / 64;          // 1563 gemm m-blocks
    const int NHA = NBKT * EA;             // 125120 histogram entries

    // setup: weight packs
    setup_misc<<<384, 256, 0, stream>>>(W1, b1, Ww, bw, Wa, ba, Wc1, Wc2, W2,
                                        WcatT, bcat, Wc1T, Wc2T, W2T);

    // megaA: input GEMM overlapped with coarse dst-histogram (LDS only)
    megaA<<<EA + MB, 256, 0, stream>>>(x, WcatT, bufA, wide, attnL, bcat,
                                       ei, histA, N, E);

    // scan histA (bucket-major) -> per-(bucket,block) bases, in place
    int nbA = (NHA + 1023) / 1024;
    scan1<<<nbA, 1024, 0, stream>>>(histA, histA, bsum, NHA);
    scan_bsums<<<1, 1024, 0, stream>>>(bsum, nbA);
    scan_add<<<nbA, 1024, 0, stream>>>(histA, bsum, NHA, -1);

    // coarse scatter into cs[]
    scatterA<<<EA, 256, 0, stream>>>(ei, ew, histA, cs, E);

    // fine counts + weight sums per dst -> ptr[] + dinv[] directly
    passB1<<<NBKT, 1024, 0, stream>>>(cs, histA, ptr, dinv, N, E);

    // megaB: conv1 GEMM (h0 -> tmpB, dinv-scaled) overlapped with CSR fill
    megaB<<<NBKT + MB, 256, 0, stream>>>(bufA, Wc1T, bufB, dinv,
                                         cs, histA, ptr, edges, N, N, E);
    propagate<<<(N + 3) / 4, 256, 0, stream>>>((const unsigned int*)bufB, (unsigned int*)bufA,
                                               bc1, dinv, ptr, edges, N);

    // conv layer 2
    gemm_conv<<<MB, 256, 0, stream>>>(bufA, Wc2T, bufB, dinv, N);
    propagate<<<(N + 3) / 4, 256, 0, stream>>>((const unsigned int*)bufB, (unsigned int*)bufA,
                                               bc2, dinv, ptr, edges, N);

    // final fusion: MFMA GEMM replaces scalar final_k
    gemm_final<<<MB, 256, 0, stream>>>(bufA, W2T, out, wide, attnL, b2, N);
}

// Round 6
// 773.137 us; speedup vs baseline: 1.0862x; 1.0104x over previous
//
#include <hip/hip_runtime.h>
#include <hip/hip_bf16.h>
#include <cstdint>

#define N_NODES 100000
#define N_EDGES 3200000

typedef __attribute__((ext_vector_type(8))) short short8;
typedef __attribute__((ext_vector_type(4))) float floatx4;

#define FXS 8388608.0f           // 2^23 fixed-point scale for degree accum
#define EA 320                   // coarse-count blocks
#define EPB 10000                // edges per coarse block (EA*EPB == E)
#define NBKT 391                 // dst>>8 buckets (100000>>8 = 390)

__device__ __forceinline__ unsigned short f2bf(float f) {
    unsigned u = __float_as_uint(f);
    u += 0x7fff + ((u >> 16) & 1);          // round-to-nearest-even
    return (unsigned short)(u >> 16);
}
__device__ __forceinline__ float bf2f(unsigned short s) {
    return __uint_as_float(((unsigned)s) << 16);
}
__device__ __forceinline__ float bflo(unsigned u) {
    return __uint_as_float(u << 16);
}
__device__ __forceinline__ float bfhi(unsigned u) {
    return __uint_as_float(u & 0xffff0000u);
}
__device__ __forceinline__ unsigned pack_bf2(float a, float b) {
    union { __hip_bfloat162 h2; unsigned u; } cv;
    cv.h2 = __float22bfloat162_rn(make_float2(a, b));   // v_cvt_pk_bf16_f32
    return cv.u;
}

// ------------------------------------------------------------------
// Setup: pack WcatT[192][512] / Wc1T / Wc2T / W2T (bf16, transposed)
// ------------------------------------------------------------------
__global__ void setup_misc(const float* __restrict__ W1, const float* __restrict__ b1,
                           const float* __restrict__ Ww, const float* __restrict__ bw,
                           const float* __restrict__ Wa, const float* __restrict__ ba,
                           const float* __restrict__ Wc1, const float* __restrict__ Wc2,
                           const float* __restrict__ W2,
                           unsigned short* __restrict__ WcatT, float* __restrict__ bcat,
                           unsigned short* __restrict__ Wc1T, unsigned short* __restrict__ Wc2T,
                           unsigned short* __restrict__ W2T) {
    int bid = blockIdx.x, tid = threadIdx.x;
    if (bid < 192) {
        int c = bid;
        for (int kk = tid; kk < 512; kk += 256) {
            float v;
            if (c < 128)      v = W1[kk * 128 + c];
            else if (c < 168) v = Ww[kk * 40 + (c - 128)];
            else if (c < 170) v = Wa[kk * 2 + (c - 168)];
            else              v = 0.f;
            WcatT[(size_t)c * 512 + kk] = f2bf(v);
        }
        if (tid == 0) {
            float b;
            if (c < 128)      b = b1[c];
            else if (c < 168) b = bw[c - 128];
            else if (c < 170) b = ba[c - 168];
            else              b = 0.f;
            bcat[c] = b;
        }
    } else if (bid < 320) {
        int c = bid - 192;
        if (tid < 128) Wc1T[(size_t)c * 128 + tid] = f2bf(Wc1[tid * 128 + c]);
        else { int k = tid - 128; Wc2T[(size_t)c * 128 + k] = f2bf(Wc2[k * 128 + c]); }
    } else {
        int c = bid - 320;                    // 0..63
        if (tid < 128)
            W2T[(size_t)c * 128 + tid] = (c < 40) ? f2bf(W2[tid * 40 + c])
                                                  : (unsigned short)0;
    }
}

// ------------------------------------------------------------------
// MFMA bf16 GEMM body: tile 64(M) x (32*NT)(N), K-step 32, 4 waves.
// A: LDS double-buffer, ONE barrier per K-step, 2-deep register
//    prefetch (A(k+2) issued at iter k).
// B: direct per-wave global loads (L2-resident weights), issued FIRST
//    each iter so the MFMA's vmcnt wait leaves the A prefetch in
//    flight (vmcnt retires in order).
// EPI 0: C0 bf16 [M][128] = rowscale[m] * val
// EPI 1: n<128 -> relu+bias -> C0 bf16; n<168 -> C1 fp32; n<170 -> C2 fp32
// EPI 2: final fusion: C1=out, C2=wide, bias=b2, rowscale=attnL (2/row)
// ------------------------------------------------------------------
template <int EPI, int NT, int AF32>
__device__ __forceinline__ void gemm_body(
    int mblk, const void* __restrict__ Avoid, const unsigned short* __restrict__ BT,
    int M, int K,
    unsigned short* __restrict__ C0, float* __restrict__ C1, float* __restrict__ C2,
    const float* __restrict__ bias, const float* __restrict__ rowscale) {
    __shared__ __align__(16) unsigned short Ast[2][64 * 40];

    int tid = threadIdx.x;
    int m0 = mblk * 64;
    int wave = tid >> 6, lane = tid & 63;
    int quad = lane >> 4, mi = lane & 15;
    int wm = (wave >> 1) * 32;
    int wn = (wave & 1) * (16 * NT);

    int srow = tid >> 2;          // 0..63
    int sk8 = (tid & 3) * 8;      // 0,8,16,24

    int arow = m0 + srow; if (arow >= M) arow = M - 1;

    const float* Afp = (const float*)Avoid + (size_t)arow * K + sk8;
    const unsigned short* Abp = (const unsigned short*)Avoid + (size_t)arow * K + sk8;
    // per-wave B fragment base: row (wn + mi), col quad*8; nt adds 16 rows
    const unsigned short* Bfp = BT + (size_t)(wn + mi) * K + quad * 8;

    const int nk = K >> 5;

    // stage K-step 0 into Ast[0]
    if (AF32) {
        float4 f0 = *(const float4*)(Afp);
        float4 f1 = *(const float4*)(Afp + 4);
        uint4 pk;
        pk.x = pack_bf2(f0.x, f0.y); pk.y = pack_bf2(f0.z, f0.w);
        pk.z = pack_bf2(f1.x, f1.y); pk.w = pack_bf2(f1.z, f1.w);
        *(uint4*)&Ast[0][srow * 40 + sk8] = pk;
    } else {
        *(uint4*)&Ast[0][srow * 40 + sk8] = *(const uint4*)(Abp);
    }
    // issue A(1) prefetch before the barrier (hides under first iter)
    float4 pA0, pA1; uint4 pAu;
    if (nk > 1) {
        if (AF32) { pA0 = *(const float4*)(Afp + 32); pA1 = *(const float4*)(Afp + 36); }
        else      { pAu = *(const uint4*)(Abp + 32); }
    }
    __syncthreads();

    floatx4 acc[2][NT] = {};

    int cur = 0;
    for (int k = 0; k < nk; ++k) {
        int kc = k << 5;
        // B fragments FIRST (needed this iter) -> MFMA waits only for
        // these; the younger A prefetch stays outstanding.
        uint4 bv[NT];
#pragma unroll
        for (int nt = 0; nt < NT; ++nt)
            bv[nt] = *(const uint4*)(Bfp + (size_t)nt * 16 * K + kc);
        // A(k+2) issue (2-deep)
        float4 nA0, nA1; uint4 nAu;
        if (k + 2 < nk) {
            if (AF32) {
                nA0 = *(const float4*)(Afp + kc + 64);
                nA1 = *(const float4*)(Afp + kc + 68);
            } else {
                nAu = *(const uint4*)(Abp + kc + 64);
            }
        }

        short8 a0 = *(const short8*)&Ast[cur][(wm + mi) * 40 + quad * 8];
        short8 a1 = *(const short8*)&Ast[cur][(wm + 16 + mi) * 40 + quad * 8];
#pragma unroll
        for (int nt = 0; nt < NT; ++nt) {
            short8 b = *(const short8*)&bv[nt];
            acc[0][nt] = __builtin_amdgcn_mfma_f32_16x16x32_bf16(a0, b, acc[0][nt], 0, 0, 0);
            acc[1][nt] = __builtin_amdgcn_mfma_f32_16x16x32_bf16(a1, b, acc[1][nt], 0, 0, 0);
        }
        if (k + 1 < nk) {
            // commit A(k+1) (issued 2 iters ago; complete by in-order
            // retirement once this iter's B arrived)
            if (AF32) {
                uint4 pk;
                pk.x = pack_bf2(pA0.x, pA0.y); pk.y = pack_bf2(pA0.z, pA0.w);
                pk.z = pack_bf2(pA1.x, pA1.y); pk.w = pack_bf2(pA1.z, pA1.w);
                *(uint4*)&Ast[cur ^ 1][srow * 40 + sk8] = pk;
            } else {
                *(uint4*)&Ast[cur ^ 1][srow * 40 + sk8] = pAu;
            }
            __syncthreads();
            cur ^= 1;
            if (AF32) { pA0 = nA0; pA1 = nA1; }
            else      { pAu = nAu; }
        }
    }

#pragma unroll
    for (int mt = 0; mt < 2; ++mt) {
#pragma unroll
        for (int nt = 0; nt < NT; ++nt) {
            floatx4 v = acc[mt][nt];
            int gn = wn + nt * 16 + mi;
#pragma unroll
            for (int r = 0; r < 4; ++r) {
                int gm = m0 + wm + mt * 16 + quad * 4 + r;
                if (gm >= M) continue;
                float val = v[r];
                if (EPI == 0) {
                    C0[(size_t)gm * 128 + gn] = f2bf(rowscale[gm] * val);
                } else if (EPI == 1) {
                    val += bias[gn];
                    if (gn < 128)      C0[(size_t)gm * 128 + gn] = f2bf(fmaxf(val, 0.f));
                    else if (gn < 168) C1[(size_t)gm * 40 + (gn - 128)] = val;
                    else if (gn < 170) C2[(size_t)gm * 2 + (gn - 168)] = val;
                } else {
                    if (gn < 40) {
                        float l0 = rowscale[gm * 2], l1 = rowscale[gm * 2 + 1];
                        float mx = fmaxf(l0, l1);
                        float e0 = __expf(l0 - mx), e1 = __expf(l1 - mx);
                        float inv = 1.f / (e0 + e1);
                        C1[(size_t)gm * 40 + gn] =
                            (val + bias[gn]) * (e0 * inv) +
                            C2[(size_t)gm * 40 + gn] * (e1 * inv);
                    }
                }
            }
        }
    }
}

// ------------------------------------------------------------------
// megaA: bid < EA -> coarse histogram of dst>>8 into LDS, dump to
// histA[k*EA + bid] (plain stores, no global atomics).
// bid >= EA -> input GEMM (x -> h0/wide/attnL).
// ------------------------------------------------------------------
__global__ __launch_bounds__(256, 4) void megaA(
    const float* __restrict__ x, const unsigned short* __restrict__ WcatT,
    unsigned short* __restrict__ h0, float* __restrict__ wide, float* __restrict__ attnL,
    const float* __restrict__ bcat, const int* __restrict__ ei,
    int* __restrict__ histA, int M, int e) {
    int bid = blockIdx.x;
    if (bid >= EA) {
        gemm_body<1, 6, 1>(bid - EA, x, WcatT, M, 512, h0, wide, attnL, bcat, nullptr);
        return;
    }
    __shared__ unsigned lh[NBKT];
    int tid = threadIdx.x;
    for (int i = tid; i < NBKT; i += 256) lh[i] = 0;
    __syncthreads();
    int base = bid * EPB, end = base + EPB; if (end > e) end = e;
    for (int i = base + tid; i < end; i += 256) {
        int d = ei[e + i];
        atomicAdd(&lh[d >> 8], 1u);
    }
    __syncthreads();
    for (int k = tid; k < NBKT; k += 256) histA[k * EA + bid] = (int)lh[k];
}

// ------------------------------------------------------------------
// scatterA: re-read edge range, rank within (bucket, block) via LDS
// fetch-add, scatter (src | dlow<<24, w) into coarse-sorted cs[].
// ------------------------------------------------------------------
__global__ __launch_bounds__(256) void scatterA(
    const int* __restrict__ ei, const float* __restrict__ ew,
    const int* __restrict__ offA, uint2* __restrict__ cs, int e) {
    int bid = blockIdx.x, tid = threadIdx.x;
    __shared__ unsigned lh[NBKT];
    __shared__ int lo[NBKT];
    for (int i = tid; i < NBKT; i += 256) { lh[i] = 0; lo[i] = offA[i * EA + bid]; }
    __syncthreads();
    int base = bid * EPB, end = base + EPB; if (end > e) end = e;
    for (int i = base + tid; i < end; i += 256) {
        int d = ei[e + i];
        int r = ei[i];
        float w = ew[i];
        int k = d >> 8;
        unsigned lr = atomicAdd(&lh[k], 1u);
        cs[lo[k] + (int)lr] = make_uint2((unsigned)r | ((unsigned)(d & 255) << 24),
                                         __float_as_uint(w));
    }
}

// ------------------------------------------------------------------
// passB1: one block per bucket; fine counts + fixed-point weight sums,
// then intra-bucket exclusive scan -> ptr[] and dinv[] directly.
// ------------------------------------------------------------------
__global__ __launch_bounds__(1024) void passB1(
    const uint2* __restrict__ cs, const int* __restrict__ offA,
    int* __restrict__ ptr, float* __restrict__ dinv, int n, int e) {
    int k = blockIdx.x, tid = threadIdx.x;
    __shared__ unsigned lc[256], lw[256];
    __shared__ int ls[256];
    if (tid < 256) { lc[tid] = 0; lw[tid] = 0; }
    __syncthreads();
    int start = offA[k * EA];
    int end = (k == NBKT - 1) ? e : offA[(k + 1) * EA];
    for (int i = start + tid; i < end; i += 1024) {
        uint2 u = cs[i];
        int dlow = u.x >> 24;
        unsigned fx = (unsigned)(__uint_as_float(u.y) * FXS);
        atomicAdd(&lc[dlow], 1u);
        atomicAdd(&lw[dlow], fx);
    }
    __syncthreads();
    int v = (tid < 256) ? (int)lc[tid] : 0;
    if (tid < 256) ls[tid] = v;
    __syncthreads();
    for (int off = 1; off < 256; off <<= 1) {
        int t = (tid < 256 && tid >= off) ? ls[tid - off] : 0;
        __syncthreads();
        if (tid < 256) ls[tid] += t;
        __syncthreads();
    }
    if (tid < 256) {
        int d = (k << 8) + tid;
        if (d < n) {
            ptr[d]  = start + ls[tid] - v;       // exclusive
            dinv[d] = rsqrtf(1.0f + (float)lw[tid] * (1.0f / FXS));
        }
    }
    if (k == NBKT - 1 && tid == 0) ptr[n] = e;
}

// ------------------------------------------------------------------
// megaB: bid < NBKT -> fine scatter (CSR fill) via LDS ranks, writes go
// into the contiguous per-bucket region of edges[].
// bid >= NBKT -> conv1 GEMM (h0 -> tmpB, dinv rowscale).
// ------------------------------------------------------------------
__global__ __launch_bounds__(256, 4) void megaB(
    const unsigned short* __restrict__ h0, const unsigned short* __restrict__ Wc1T,
    unsigned short* __restrict__ tmpB, const float* __restrict__ dinv,
    const uint2* __restrict__ cs, const int* __restrict__ offA,
    const int* __restrict__ ptr, uint2* __restrict__ edges, int M, int n, int e) {
    int bid = blockIdx.x;
    if (bid >= NBKT) {
        gemm_body<0, 4, 0>(bid - NBKT, h0, Wc1T, M, 128, tmpB, nullptr, nullptr, nullptr, dinv);
        return;
    }
    int k = bid, tid = threadIdx.x;
    __shared__ unsigned lc[256];
    __shared__ int lp[256];
    { lc[tid] = 0; int d = (k << 8) + tid; lp[tid] = (d < n) ? ptr[d] : 0; }
    __syncthreads();
    int start = offA[k * EA];
    int end = (k == NBKT - 1) ? e : offA[(k + 1) * EA];
    for (int i = start + tid; i < end; i += 256) {
        uint2 u = cs[i];
        int dlow = u.x >> 24;
        unsigned src = u.x & 0x00FFFFFFu;
        unsigned lr = atomicAdd(&lc[dlow], 1u);
        edges[lp[dlow] + (int)lr] = make_uint2(src, u.y);
    }
}

__global__ __launch_bounds__(256, 4) void gemm_conv(
    const unsigned short* __restrict__ A, const unsigned short* __restrict__ BT,
    unsigned short* __restrict__ C0, const float* __restrict__ rowscale, int M) {
    gemm_body<0, 4, 0>(blockIdx.x, A, BT, M, 128, C0, nullptr, nullptr, nullptr, rowscale);
}

// ------------------------------------------------------------------
// Final layer as MFMA GEMM: out = (h2 @ W2 + b2)*a0 + wide*a1
// ------------------------------------------------------------------
__global__ __launch_bounds__(256, 4) void gemm_final(
    const unsigned short* __restrict__ A, const unsigned short* __restrict__ W2T,
    float* __restrict__ out, float* __restrict__ wide,
    const float* __restrict__ attnL, const float* __restrict__ b2, int M) {
    gemm_body<2, 2, 0>(blockIdx.x, A, W2T, M, 128, nullptr, out, wide, b2, attnL);
}

// ------------------------------------------------------------------
// Generic int exclusive scan (1024-wide blocks + block-sum fixup).
// Used only for the histA (bucket,block) offset table.
// ------------------------------------------------------------------
__global__ void scan1(const int* __restrict__ in, int* __restrict__ out,
                      int* __restrict__ bsum, int n) {
    __shared__ int s[1024];
    int tid = threadIdx.x;
    int i = blockIdx.x * 1024 + tid;
    int v = (i < n) ? in[i] : 0;
    s[tid] = v;
    __syncthreads();
    for (int off = 1; off < 1024; off <<= 1) {
        int t = (tid >= off) ? s[tid - off] : 0;
        __syncthreads();
        s[tid] += t;
        __syncthreads();
    }
    if (i < n) out[i] = s[tid] - v;              // exclusive
    if (tid == 1023) bsum[blockIdx.x] = s[1023];
}

__global__ void scan_bsums(int* bsum, int nb) {
    __shared__ int s[1024];
    int tid = threadIdx.x;
    int v = (tid < nb) ? bsum[tid] : 0;
    s[tid] = v;
    __syncthreads();
    for (int off = 1; off < 1024; off <<= 1) {
        int t = (tid >= off) ? s[tid - off] : 0;
        __syncthreads();
        s[tid] += t;
        __syncthreads();
    }
    if (tid < nb) bsum[tid] = s[tid] - v;        // exclusive
}

__global__ void scan_add(int* __restrict__ out, const int* __restrict__ bsum,
                         int n, int tailv) {
    int i = blockIdx.x * 1024 + threadIdx.x;
    if (i < n) out[i] += bsum[blockIdx.x];
    if (i == 0 && tailv >= 0) out[n] = tailv;
}

// ------------------------------------------------------------------
// GCN propagation, dst-CSR, bf16 messages, dinv pre-folded into rows:
// out[d] = relu(dinv[d] * (tmp'[d] + sum ew*tmp'[src]) + bias)
// One WAVE per dst node, 8-deep edge unroll for MLP.
// ------------------------------------------------------------------
__global__ __launch_bounds__(256) void propagate(
    const unsigned int* __restrict__ tmp2,    // [M][64] packed bf16x2 (dinv-scaled)
    unsigned int* __restrict__ out2,
    const float* __restrict__ bias, const float* __restrict__ dinv,
    const int* __restrict__ ptr, const uint2* __restrict__ edges, int n) {
    int wave = threadIdx.x >> 6, lane = threadIdx.x & 63;
    int d = blockIdx.x * 4 + wave;
    if (d >= n) return;

    unsigned u = tmp2[(size_t)d * 64 + lane];   // self loop
    float acc0 = bflo(u);
    float acc1 = bfhi(u);

    int p = ptr[d], p1 = ptr[d + 1];
    for (; p + 8 <= p1; p += 8) {
        uint2 q[8];
#pragma unroll
        for (int j = 0; j < 8; ++j) q[j] = edges[p + j];
        unsigned rv[8];
#pragma unroll
        for (int j = 0; j < 8; ++j) rv[j] = tmp2[(size_t)q[j].x * 64 + lane];
#pragma unroll
        for (int j = 0; j < 8; ++j) {
            float w = __uint_as_float(q[j].y);
            acc0 += w * bflo(rv[j]); acc1 += w * bfhi(rv[j]);
        }
    }
    for (; p < p1; ++p) {
        uint2 q = edges[p];
        unsigned a = tmp2[(size_t)q.x * 64 + lane];
        float w = __uint_as_float(q.y);
        acc0 += w * bflo(a); acc1 += w * bfhi(a);
    }
    float di = dinv[d];
    float v0 = fmaxf(di * acc0 + bias[2 * lane], 0.f);
    float v1 = fmaxf(di * acc1 + bias[2 * lane + 1], 0.f);
    out2[(size_t)d * 64 + lane] = (unsigned)f2bf(v0) | ((unsigned)f2bf(v1) << 16);
}

// ------------------------------------------------------------------
extern "C" void kernel_launch(void* const* d_in, const int* in_sizes, int n_in,
                              void* d_out, int out_size, void* d_ws, size_t ws_size,
                              hipStream_t stream) {
    (void)in_sizes; (void)n_in; (void)out_size; (void)ws_size;
    const float* x   = (const float*)d_in[0];
    const int*   ei  = (const int*)d_in[1];
    const float* ew  = (const float*)d_in[2];
    const float* W1  = (const float*)d_in[3];
    const float* b1  = (const float*)d_in[4];
    const float* Wc1 = (const float*)d_in[5];
    const float* bc1 = (const float*)d_in[6];
    const float* Wc2 = (const float*)d_in[7];
    const float* bc2 = (const float*)d_in[8];
    const float* W2  = (const float*)d_in[9];
    const float* b2  = (const float*)d_in[10];
    const float* Ww  = (const float*)d_in[11];
    const float* bw  = (const float*)d_in[12];
    const float* Wa  = (const float*)d_in[13];
    const float* ba  = (const float*)d_in[14];
    float* out = (float*)d_out;

    const int N = N_NODES, E = N_EDGES;
    char* ws = (char*)d_ws;
    size_t off = 0;
    auto alloc = [&](size_t bytes) -> void* {
        void* p = ws + off;
        off = (off + bytes + 255) & ~(size_t)255;
        return p;
    };
    unsigned short* bufA = (unsigned short*)alloc((size_t)N * 128 * 2);
    unsigned short* bufB = (unsigned short*)alloc((size_t)N * 128 * 2);
    float* wide  = (float*)alloc((size_t)N * 40 * 4);
    float* attnL = (float*)alloc((size_t)N * 2 * 4);
    float* dinv  = (float*)alloc((size_t)N * 4);
    int*   histA = (int*)alloc((size_t)NBKT * EA * 4);   // scanned in place -> offA
    uint2* cs    = (uint2*)alloc((size_t)E * 8);         // coarse bucket-sorted records
    int*   ptr   = (int*)alloc((size_t)(N + 1) * 4);
    int*   bsum  = (int*)alloc(1024 * 4);
    uint2* edges = (uint2*)alloc((size_t)E * 8);
    unsigned short* WcatT = (unsigned short*)alloc((size_t)192 * 512 * 2);
    unsigned short* Wc1T  = (unsigned short*)alloc((size_t)128 * 128 * 2);
    unsigned short* Wc2T  = (unsigned short*)alloc((size_t)128 * 128 * 2);
    unsigned short* W2T   = (unsigned short*)alloc((size_t)64 * 128 * 2);
    float* bcat  = (float*)alloc(192 * 4);

    const int MB = (N + 63) / 64;          // 1563 gemm m-blocks
    const int NHA = NBKT * EA;             // 125120 histogram entries

    // setup: weight packs
    setup_misc<<<384, 256, 0, stream>>>(W1, b1, Ww, bw, Wa, ba, Wc1, Wc2, W2,
                                        WcatT, bcat, Wc1T, Wc2T, W2T);

    // megaA: input GEMM overlapped with coarse dst-histogram (LDS only)
    megaA<<<EA + MB, 256, 0, stream>>>(x, WcatT, bufA, wide, attnL, bcat,
                                       ei, histA, N, E);

    // scan histA (bucket-major) -> per-(bucket,block) bases, in place
    int nbA = (NHA + 1023) / 1024;
    scan1<<<nbA, 1024, 0, stream>>>(histA, histA, bsum, NHA);
    scan_bsums<<<1, 1024, 0, stream>>>(bsum, nbA);
    scan_add<<<nbA, 1024, 0, stream>>>(histA, bsum, NHA, -1);

    // coarse scatter into cs[]
    scatterA<<<EA, 256, 0, stream>>>(ei, ew, histA, cs, E);

    // fine counts + weight sums per dst -> ptr[] + dinv[] directly
    passB1<<<NBKT, 1024, 0, stream>>>(cs, histA, ptr, dinv, N, E);

    // megaB: conv1 GEMM (h0 -> tmpB, dinv-scaled) overlapped with CSR fill
    megaB<<<NBKT + MB, 256, 0, stream>>>(bufA, Wc1T, bufB, dinv,
                                         cs, histA, ptr, edges, N, N, E);
    propagate<<<(N + 3) / 4, 256, 0, stream>>>((const unsigned int*)bufB, (unsigned int*)bufA,
                                               bc1, dinv, ptr, edges, N);

    // conv layer 2
    gemm_conv<<<MB, 256, 0, stream>>>(bufA, Wc2T, bufB, dinv, N);
    propagate<<<(N + 3) / 4, 256, 0, stream>>>((const unsigned int*)bufB, (unsigned int*)bufA,
                                               bc2, dinv, ptr, edges, N);

    // final fusion: MFMA GEMM replaces scalar final_k
    gemm_final<<<MB, 256, 0, stream>>>(bufA, W2T, out, wide, attnL, b2, N);
}

// Round 7
// 738.738 us; speedup vs baseline: 1.1367x; 1.0466x over previous
//
#include <hip/hip_runtime.h>
#include <hip/hip_bf16.h>
#include <cstdint>

#define N_NODES 100000
#define N_EDGES 3200000

typedef __attribute__((ext_vector_type(8))) short short8;
typedef __attribute__((ext_vector_type(4))) float floatx4;

#define FXS 8388608.0f           // 2^23 fixed-point scale for degree accum
#define EA 320                   // coarse-count blocks
#define EPB 10000                // edges per coarse block (EA*EPB == E)
#define NBKT 391                 // dst>>8 buckets (100000>>8 = 390)

__device__ __forceinline__ unsigned short f2bf(float f) {
    unsigned u = __float_as_uint(f);
    u += 0x7fff + ((u >> 16) & 1);          // round-to-nearest-even
    return (unsigned short)(u >> 16);
}
__device__ __forceinline__ float bf2f(unsigned short s) {
    return __uint_as_float(((unsigned)s) << 16);
}
__device__ __forceinline__ float bflo(unsigned u) {
    return __uint_as_float(u << 16);
}
__device__ __forceinline__ float bfhi(unsigned u) {
    return __uint_as_float(u & 0xffff0000u);
}
__device__ __forceinline__ unsigned pack_bf2(float a, float b) {
    union { __hip_bfloat162 h2; unsigned u; } cv;
    cv.h2 = __float22bfloat162_rn(make_float2(a, b));   // v_cvt_pk_bf16_f32
    return cv.u;
}

// ------------------------------------------------------------------
// Setup: pack WcatT[192][512] / Wc1T / Wc2T / W2T (bf16, transposed)
// ------------------------------------------------------------------
__global__ void setup_misc(const float* __restrict__ W1, const float* __restrict__ b1,
                           const float* __restrict__ Ww, const float* __restrict__ bw,
                           const float* __restrict__ Wa, const float* __restrict__ ba,
                           const float* __restrict__ Wc1, const float* __restrict__ Wc2,
                           const float* __restrict__ W2,
                           unsigned short* __restrict__ WcatT, float* __restrict__ bcat,
                           unsigned short* __restrict__ Wc1T, unsigned short* __restrict__ Wc2T,
                           unsigned short* __restrict__ W2T) {
    int bid = blockIdx.x, tid = threadIdx.x;
    if (bid < 192) {
        int c = bid;
        for (int kk = tid; kk < 512; kk += 256) {
            float v;
            if (c < 128)      v = W1[kk * 128 + c];
            else if (c < 168) v = Ww[kk * 40 + (c - 128)];
            else if (c < 170) v = Wa[kk * 2 + (c - 168)];
            else              v = 0.f;
            WcatT[(size_t)c * 512 + kk] = f2bf(v);
        }
        if (tid == 0) {
            float b;
            if (c < 128)      b = b1[c];
            else if (c < 168) b = bw[c - 128];
            else if (c < 170) b = ba[c - 168];
            else              b = 0.f;
            bcat[c] = b;
        }
    } else if (bid < 320) {
        int c = bid - 192;
        if (tid < 128) Wc1T[(size_t)c * 128 + tid] = f2bf(Wc1[tid * 128 + c]);
        else { int k = tid - 128; Wc2T[(size_t)c * 128 + k] = f2bf(Wc2[k * 128 + c]); }
    } else {
        int c = bid - 320;                    // 0..63
        if (tid < 128)
            W2T[(size_t)c * 128 + tid] = (c < 40) ? f2bf(W2[tid * 40 + c])
                                                  : (unsigned short)0;
    }
}

// ------------------------------------------------------------------
// MFMA bf16 GEMM body (R2 known-good): tile 64(M) x (32*NT)(N),
// K-step 32, 4 waves, A+B LDS staged, two barriers per K-step.
// EPI 0: C0 bf16 [M][128] = rowscale[m] * val
// EPI 1: n<128 -> relu+bias -> C0 bf16; n<168 -> C1 fp32; n<170 -> C2 fp32
// EPI 2: final fusion: C1=out, C2=wide, bias=b2, rowscale=attnL (2/row)
// ------------------------------------------------------------------
template <int EPI, int NT, int AF32>
__device__ __forceinline__ void gemm_body(
    int mblk, const void* __restrict__ Avoid, const unsigned short* __restrict__ BT,
    int M, int K,
    unsigned short* __restrict__ C0, float* __restrict__ C1, float* __restrict__ C2,
    const float* __restrict__ bias, const float* __restrict__ rowscale) {
    constexpr int NB = 32 * NT;
    __shared__ __align__(16) unsigned short Ast[64 * 40];
    __shared__ __align__(16) unsigned short Bst[NB * 40];

    int tid = threadIdx.x;
    int m0 = mblk * 64;
    int wave = tid >> 6, lane = tid & 63;
    int quad = lane >> 4, mi = lane & 15;
    int wm = (wave >> 1) * 32;
    int wn = (wave & 1) * (16 * NT);

    int srow = tid >> 2;
    int sk8 = (tid & 3) * 8;

    int arow = m0 + srow; if (arow >= M) arow = M - 1;

    floatx4 acc[2][NT] = {};

    for (int kc = 0; kc < K; kc += 32) {
        if (AF32) {
            const float* Af = (const float*)Avoid;
            const float4* ap = (const float4*)(Af + (size_t)arow * K + kc + sk8);
            float4 f0 = ap[0], f1 = ap[1];
            uint4 pk;
            pk.x = pack_bf2(f0.x, f0.y);
            pk.y = pack_bf2(f0.z, f0.w);
            pk.z = pack_bf2(f1.x, f1.y);
            pk.w = pack_bf2(f1.z, f1.w);
            *(uint4*)&Ast[srow * 40 + sk8] = pk;
        } else {
            const unsigned short* Ab = (const unsigned short*)Avoid;
            uint4 av = *(const uint4*)(Ab + (size_t)arow * K + kc + sk8);
            *(uint4*)&Ast[srow * 40 + sk8] = av;
        }
#pragma unroll
        for (int i = tid; i < NB * 4; i += 256) {
            int brow = i >> 2;
            int bk8 = (i & 3) * 8;
            uint4 bv = *(const uint4*)(BT + (size_t)brow * K + kc + bk8);
            *(uint4*)&Bst[brow * 40 + bk8] = bv;
        }
        __syncthreads();

        short8 a0 = *(const short8*)&Ast[(wm + mi) * 40 + quad * 8];
        short8 a1 = *(const short8*)&Ast[(wm + 16 + mi) * 40 + quad * 8];
#pragma unroll
        for (int nt = 0; nt < NT; ++nt) {
            short8 b = *(const short8*)&Bst[(wn + nt * 16 + mi) * 40 + quad * 8];
            acc[0][nt] = __builtin_amdgcn_mfma_f32_16x16x32_bf16(a0, b, acc[0][nt], 0, 0, 0);
            acc[1][nt] = __builtin_amdgcn_mfma_f32_16x16x32_bf16(a1, b, acc[1][nt], 0, 0, 0);
        }
        __syncthreads();
    }

#pragma unroll
    for (int mt = 0; mt < 2; ++mt) {
#pragma unroll
        for (int nt = 0; nt < NT; ++nt) {
            floatx4 v = acc[mt][nt];
            int gn = wn + nt * 16 + mi;
#pragma unroll
            for (int r = 0; r < 4; ++r) {
                int gm = m0 + wm + mt * 16 + quad * 4 + r;
                if (gm >= M) continue;
                float val = v[r];
                if (EPI == 0) {
                    C0[(size_t)gm * 128 + gn] = f2bf(rowscale[gm] * val);
                } else if (EPI == 1) {
                    val += bias[gn];
                    if (gn < 128)      C0[(size_t)gm * 128 + gn] = f2bf(fmaxf(val, 0.f));
                    else if (gn < 168) C1[(size_t)gm * 40 + (gn - 128)] = val;
                    else if (gn < 170) C2[(size_t)gm * 2 + (gn - 168)] = val;
                } else {
                    if (gn < 40) {
                        float l0 = rowscale[gm * 2], l1 = rowscale[gm * 2 + 1];
                        float mx = fmaxf(l0, l1);
                        float e0 = __expf(l0 - mx), e1 = __expf(l1 - mx);
                        float inv = 1.f / (e0 + e1);
                        C1[(size_t)gm * 40 + gn] =
                            (val + bias[gn]) * (e0 * inv) +
                            C2[(size_t)gm * 40 + gn] * (e1 * inv);
                    }
                }
            }
        }
    }
}

// ------------------------------------------------------------------
// megaA: bid < EA -> coarse histogram of dst>>8 into LDS, dump to
// histA[k*EA + bid] (plain stores, no global atomics).
// bid >= EA -> input GEMM (x -> h0/wide/attnL).
// ------------------------------------------------------------------
__global__ __launch_bounds__(256) void megaA(
    const float* __restrict__ x, const unsigned short* __restrict__ WcatT,
    unsigned short* __restrict__ h0, float* __restrict__ wide, float* __restrict__ attnL,
    const float* __restrict__ bcat, const int* __restrict__ ei,
    int* __restrict__ histA, int M, int e) {
    int bid = blockIdx.x;
    if (bid >= EA) {
        gemm_body<1, 6, 1>(bid - EA, x, WcatT, M, 512, h0, wide, attnL, bcat, nullptr);
        return;
    }
    __shared__ unsigned lh[NBKT];
    int tid = threadIdx.x;
    for (int i = tid; i < NBKT; i += 256) lh[i] = 0;
    __syncthreads();
    int base = bid * EPB, end = base + EPB; if (end > e) end = e;
    for (int i = base + tid; i < end; i += 256) {
        int d = ei[e + i];
        atomicAdd(&lh[d >> 8], 1u);
    }
    __syncthreads();
    for (int k = tid; k < NBKT; k += 256) histA[k * EA + bid] = (int)lh[k];
}

// ------------------------------------------------------------------
// scatterA: re-read edge range, rank within (bucket, block) via LDS
// fetch-add, scatter (src | dlow<<24, w) into coarse-sorted cs[].
// ------------------------------------------------------------------
__global__ __launch_bounds__(256) void scatterA(
    const int* __restrict__ ei, const float* __restrict__ ew,
    const int* __restrict__ offA, uint2* __restrict__ cs, int e) {
    int bid = blockIdx.x, tid = threadIdx.x;
    __shared__ unsigned lh[NBKT];
    __shared__ int lo[NBKT];
    for (int i = tid; i < NBKT; i += 256) { lh[i] = 0; lo[i] = offA[i * EA + bid]; }
    __syncthreads();
    int base = bid * EPB, end = base + EPB; if (end > e) end = e;
    for (int i = base + tid; i < end; i += 256) {
        int d = ei[e + i];
        int r = ei[i];
        float w = ew[i];
        int k = d >> 8;
        unsigned lr = atomicAdd(&lh[k], 1u);
        cs[lo[k] + (int)lr] = make_uint2((unsigned)r | ((unsigned)(d & 255) << 24),
                                         __float_as_uint(w));
    }
}

// ------------------------------------------------------------------
// passB1: one block per bucket; fine counts + fixed-point weight sums,
// then intra-bucket exclusive scan -> ptr[] and dinv[] directly.
// ------------------------------------------------------------------
__global__ __launch_bounds__(1024) void passB1(
    const uint2* __restrict__ cs, const int* __restrict__ offA,
    int* __restrict__ ptr, float* __restrict__ dinv, int n, int e) {
    int k = blockIdx.x, tid = threadIdx.x;
    __shared__ unsigned lc[256], lw[256];
    __shared__ int ls[256];
    if (tid < 256) { lc[tid] = 0; lw[tid] = 0; }
    __syncthreads();
    int start = offA[k * EA];
    int end = (k == NBKT - 1) ? e : offA[(k + 1) * EA];
    for (int i = start + tid; i < end; i += 1024) {
        uint2 u = cs[i];
        int dlow = u.x >> 24;
        unsigned fx = (unsigned)(__uint_as_float(u.y) * FXS);
        atomicAdd(&lc[dlow], 1u);
        atomicAdd(&lw[dlow], fx);
    }
    __syncthreads();
    int v = (tid < 256) ? (int)lc[tid] : 0;
    if (tid < 256) ls[tid] = v;
    __syncthreads();
    for (int off = 1; off < 256; off <<= 1) {
        int t = (tid < 256 && tid >= off) ? ls[tid - off] : 0;
        __syncthreads();
        if (tid < 256) ls[tid] += t;
        __syncthreads();
    }
    if (tid < 256) {
        int d = (k << 8) + tid;
        if (d < n) {
            ptr[d]  = start + ls[tid] - v;       // exclusive
            dinv[d] = rsqrtf(1.0f + (float)lw[tid] * (1.0f / FXS));
        }
    }
    if (k == NBKT - 1 && tid == 0) ptr[n] = e;
}

// ------------------------------------------------------------------
// megaB: bid < NBKT -> fine scatter (CSR fill) via LDS ranks, writes go
// into the contiguous per-bucket region of edges[].
// bid >= NBKT -> conv1 GEMM (h0 -> tmpB, dinv rowscale).
// ------------------------------------------------------------------
__global__ __launch_bounds__(256) void megaB(
    const unsigned short* __restrict__ h0, const unsigned short* __restrict__ Wc1T,
    unsigned short* __restrict__ tmpB, const float* __restrict__ dinv,
    const uint2* __restrict__ cs, const int* __restrict__ offA,
    const int* __restrict__ ptr, uint2* __restrict__ edges, int M, int n, int e) {
    int bid = blockIdx.x;
    if (bid >= NBKT) {
        gemm_body<0, 4, 0>(bid - NBKT, h0, Wc1T, M, 128, tmpB, nullptr, nullptr, nullptr, dinv);
        return;
    }
    int k = bid, tid = threadIdx.x;
    __shared__ unsigned lc[256];
    __shared__ int lp[256];
    { lc[tid] = 0; int d = (k << 8) + tid; lp[tid] = (d < n) ? ptr[d] : 0; }
    __syncthreads();
    int start = offA[k * EA];
    int end = (k == NBKT - 1) ? e : offA[(k + 1) * EA];
    for (int i = start + tid; i < end; i += 256) {
        uint2 u = cs[i];
        int dlow = u.x >> 24;
        unsigned src = u.x & 0x00FFFFFFu;
        unsigned lr = atomicAdd(&lc[dlow], 1u);
        edges[lp[dlow] + (int)lr] = make_uint2(src, u.y);
    }
}

__global__ __launch_bounds__(256) void gemm_conv(
    const unsigned short* __restrict__ A, const unsigned short* __restrict__ BT,
    unsigned short* __restrict__ C0, const float* __restrict__ rowscale, int M) {
    gemm_body<0, 4, 0>(blockIdx.x, A, BT, M, 128, C0, nullptr, nullptr, nullptr, rowscale);
}

// ------------------------------------------------------------------
// Final layer as MFMA GEMM: out = (h2 @ W2 + b2)*a0 + wide*a1
// ------------------------------------------------------------------
__global__ __launch_bounds__(256) void gemm_final(
    const unsigned short* __restrict__ A, const unsigned short* __restrict__ W2T,
    float* __restrict__ out, float* __restrict__ wide,
    const float* __restrict__ attnL, const float* __restrict__ b2, int M) {
    gemm_body<2, 2, 0>(blockIdx.x, A, W2T, M, 128, nullptr, out, wide, b2, attnL);
}

// ------------------------------------------------------------------
// Generic int exclusive scan (1024-wide blocks + block-sum fixup).
// Used only for the histA (bucket,block) offset table.
// ------------------------------------------------------------------
__global__ void scan1(const int* __restrict__ in, int* __restrict__ out,
                      int* __restrict__ bsum, int n) {
    __shared__ int s[1024];
    int tid = threadIdx.x;
    int i = blockIdx.x * 1024 + tid;
    int v = (i < n) ? in[i] : 0;
    s[tid] = v;
    __syncthreads();
    for (int off = 1; off < 1024; off <<= 1) {
        int t = (tid >= off) ? s[tid - off] : 0;
        __syncthreads();
        s[tid] += t;
        __syncthreads();
    }
    if (i < n) out[i] = s[tid] - v;              // exclusive
    if (tid == 1023) bsum[blockIdx.x] = s[1023];
}

__global__ void scan_bsums(int* bsum, int nb) {
    __shared__ int s[1024];
    int tid = threadIdx.x;
    int v = (tid < nb) ? bsum[tid] : 0;
    s[tid] = v;
    __syncthreads();
    for (int off = 1; off < 1024; off <<= 1) {
        int t = (tid >= off) ? s[tid - off] : 0;
        __syncthreads();
        s[tid] += t;
        __syncthreads();
    }
    if (tid < nb) bsum[tid] = s[tid] - v;        // exclusive
}

__global__ void scan_add(int* __restrict__ out, const int* __restrict__ bsum,
                         int n, int tailv) {
    int i = blockIdx.x * 1024 + threadIdx.x;
    if (i < n) out[i] += bsum[blockIdx.x];
    if (i == 0 && tailv >= 0) out[n] = tailv;
}

// ------------------------------------------------------------------
// GCN propagation, dst-CSR, bf16 messages, dinv pre-folded into rows:
// out[d] = relu(dinv[d] * (tmp'[d] + sum ew*tmp'[src]) + bias)
// One WAVE per dst node, 16-deep edge unroll (16 in-flight gathers).
// ------------------------------------------------------------------
__global__ __launch_bounds__(256) void propagate(
    const unsigned int* __restrict__ tmp2,    // [M][64] packed bf16x2 (dinv-scaled)
    unsigned int* __restrict__ out2,
    const float* __restrict__ bias, const float* __restrict__ dinv,
    const int* __restrict__ ptr, const uint2* __restrict__ edges, int n) {
    int wave = threadIdx.x >> 6, lane = threadIdx.x & 63;
    int d = blockIdx.x * 4 + wave;
    if (d >= n) return;

    unsigned u = tmp2[(size_t)d * 64 + lane];   // self loop
    float acc0 = bflo(u);
    float acc1 = bfhi(u);

    int p = ptr[d], p1 = ptr[d + 1];
    for (; p + 16 <= p1; p += 16) {
        uint2 q[16];
#pragma unroll
        for (int j = 0; j < 16; ++j) q[j] = edges[p + j];
        unsigned rv[16];
#pragma unroll
        for (int j = 0; j < 16; ++j) rv[j] = tmp2[(size_t)q[j].x * 64 + lane];
#pragma unroll
        for (int j = 0; j < 16; ++j) {
            float w = __uint_as_float(q[j].y);
            acc0 += w * bflo(rv[j]); acc1 += w * bfhi(rv[j]);
        }
    }
    for (; p + 4 <= p1; p += 4) {
        uint2 q[4];
#pragma unroll
        for (int j = 0; j < 4; ++j) q[j] = edges[p + j];
        unsigned rv[4];
#pragma unroll
        for (int j = 0; j < 4; ++j) rv[j] = tmp2[(size_t)q[j].x * 64 + lane];
#pragma unroll
        for (int j = 0; j < 4; ++j) {
            float w = __uint_as_float(q[j].y);
            acc0 += w * bflo(rv[j]); acc1 += w * bfhi(rv[j]);
        }
    }
    for (; p < p1; ++p) {
        uint2 q = edges[p];
        unsigned a = tmp2[(size_t)q.x * 64 + lane];
        float w = __uint_as_float(q.y);
        acc0 += w * bflo(a); acc1 += w * bfhi(a);
    }
    float di = dinv[d];
    float v0 = fmaxf(di * acc0 + bias[2 * lane], 0.f);
    float v1 = fmaxf(di * acc1 + bias[2 * lane + 1], 0.f);
    out2[(size_t)d * 64 + lane] = (unsigned)f2bf(v0) | ((unsigned)f2bf(v1) << 16);
}

// ------------------------------------------------------------------
extern "C" void kernel_launch(void* const* d_in, const int* in_sizes, int n_in,
                              void* d_out, int out_size, void* d_ws, size_t ws_size,
                              hipStream_t stream) {
    (void)in_sizes; (void)n_in; (void)out_size; (void)ws_size;
    const float* x   = (const float*)d_in[0];
    const int*   ei  = (const int*)d_in[1];
    const float* ew  = (const float*)d_in[2];
    const float* W1  = (const float*)d_in[3];
    const float* b1  = (const float*)d_in[4];
    const float* Wc1 = (const float*)d_in[5];
    const float* bc1 = (const float*)d_in[6];
    const float* Wc2 = (const float*)d_in[7];
    const float* bc2 = (const float*)d_in[8];
    const float* W2  = (const float*)d_in[9];
    const float* b2  = (const float*)d_in[10];
    const float* Ww  = (const float*)d_in[11];
    const float* bw  = (const float*)d_in[12];
    const float* Wa  = (const float*)d_in[13];
    const float* ba  = (const float*)d_in[14];
    float* out = (float*)d_out;

    const int N = N_NODES, E = N_EDGES;
    char* ws = (char*)d_ws;
    size_t off = 0;
    auto alloc = [&](size_t bytes) -> void* {
        void* p = ws + off;
        off = (off + bytes + 255) & ~(size_t)255;
        return p;
    };
    unsigned short* bufA = (unsigned short*)alloc((size_t)N * 128 * 2);
    unsigned short* bufB = (unsigned short*)alloc((size_t)N * 128 * 2);
    float* wide  = (float*)alloc((size_t)N * 40 * 4);
    float* attnL = (float*)alloc((size_t)N * 2 * 4);
    float* dinv  = (float*)alloc((size_t)N * 4);
    int*   histA = (int*)alloc((size_t)NBKT * EA * 4);   // scanned in place -> offA
    uint2* cs    = (uint2*)alloc((size_t)E * 8);         // coarse bucket-sorted records
    int*   ptr   = (int*)alloc((size_t)(N + 1) * 4);
    int*   bsum  = (int*)alloc(1024 * 4);
    uint2* edges = (uint2*)alloc((size_t)E * 8);
    unsigned short* WcatT = (unsigned short*)alloc((size_t)192 * 512 * 2);
    unsigned short* Wc1T  = (unsigned short*)alloc((size_t)128 * 128 * 2);
    unsigned short* Wc2T  = (unsigned short*)alloc((size_t)128 * 128 * 2);
    unsigned short* W2T   = (unsigned short*)alloc((size_t)64 * 128 * 2);
    float* bcat  = (float*)alloc(192 * 4);

    const int MB = (N + 63) / 64;          // 1563 gemm m-blocks
    const int NHA = NBKT * EA;             // 125120 histogram entries

    // setup: weight packs
    setup_misc<<<384, 256, 0, stream>>>(W1, b1, Ww, bw, Wa, ba, Wc1, Wc2, W2,
                                        WcatT, bcat, Wc1T, Wc2T, W2T);

    // megaA: input GEMM overlapped with coarse dst-histogram (LDS only)
    megaA<<<EA + MB, 256, 0, stream>>>(x, WcatT, bufA, wide, attnL, bcat,
                                       ei, histA, N, E);

    // scan histA (bucket-major) -> per-(bucket,block) bases, in place
    int nbA = (NHA + 1023) / 1024;
    scan1<<<nbA, 1024, 0, stream>>>(histA, histA, bsum, NHA);
    scan_bsums<<<1, 1024, 0, stream>>>(bsum, nbA);
    scan_add<<<nbA, 1024, 0, stream>>>(histA, bsum, NHA, -1);

    // coarse scatter into cs[]
    scatterA<<<EA, 256, 0, stream>>>(ei, ew, histA, cs, E);

    // fine counts + weight sums per dst -> ptr[] + dinv[] directly
    passB1<<<NBKT, 1024, 0, stream>>>(cs, histA, ptr, dinv, N, E);

    // megaB: conv1 GEMM (h0 -> tmpB, dinv-scaled) overlapped with CSR fill
    megaB<<<NBKT + MB, 256, 0, stream>>>(bufA, Wc1T, bufB, dinv,
                                         cs, histA, ptr, edges, N, N, E);
    propagate<<<(N + 3) / 4, 256, 0, stream>>>((const unsigned int*)bufB, (unsigned int*)bufA,
                                               bc1, dinv, ptr, edges, N);

    // conv layer 2
    gemm_conv<<<MB, 256, 0, stream>>>(bufA, Wc2T, bufB, dinv, N);
    propagate<<<(N + 3) / 4, 256, 0, stream>>>((const unsigned int*)bufB, (unsigned int*)bufA,
                                               bc2, dinv, ptr, edges, N);

    // final fusion: MFMA GEMM replaces scalar final_k
    gemm_final<<<MB, 256, 0, stream>>>(bufA, W2T, out, wide, attnL, b2, N);
}